// Round 1
// baseline (567.535 us; speedup 1.0000x reference)
//
#include <hip/hip_runtime.h>

#define D 256
#define KCODES 8192
#define NTOK 16384
#define QSIZE (NTOK * D)
#define NBLK 128              // screening blocks of 64 codes
#define CBS 64
// TH: candidate window. Budget (fp16 screen, cb pre-scaled 2^12 so no fp16
// subnormals): ref-rounding eta <= 3.05e-5 + 2*fp16-dot err (max-stat) ~2.4e-5
// + bf16 bmin quantization ~4e-6  => delta ~5.9e-5, need TH >= 2*delta ~1.2e-4.
// TH = 2e-4 gives ~1.7x margin. (Validated: R11 first-call passed bit-exact.)
#define TH 2e-4f
#define CBSCALE 4096.0f       // exact pow2; acc = 2^12 * dot
#define UNSCALE2 4.8828125e-4f // 2^-11 = 2 * 2^-12 (exact)
#define CCAP 4096             // per-nb candidate capacity (stat need ~170-1100)
#define PB 128                // candidates per pass2b block (32 per wave)

typedef _Float16 f16x8 __attribute__((ext_vector_type(8)));  // 8 fp16, 4 VGPRs
typedef float f32x4 __attribute__((ext_vector_type(4)));
typedef __attribute__((address_space(3))) void* lds_vp;
typedef __attribute__((address_space(1))) const void* gbl_vp;

#define P2_LDS (256 * 65 * 4)           // 66560 B: cb^T fp32 [256][65]

__device__ __forceinline__ ushort f32_to_bf16(float f) {
    unsigned u = __float_as_uint(f);
    return (ushort)((u + 0x7FFFu + ((u >> 16) & 1)) >> 16);
}
__device__ __forceinline__ ushort f32_to_f16(float f) {
    _Float16 h = (_Float16)f;          // v_cvt_f16_f32, RNE
    ushort u; __builtin_memcpy(&u, &h, 2);
    return u;
}
// race-free broadcast: v_readlane_b32 (register file, exec-independent)
__device__ __forceinline__ float rdlane(float v, int lane) {
    return __uint_as_float(__builtin_amdgcn_readlane(__float_as_uint(v), lane));
}

// ---- convert fp32 -> fp16 (RNE) with scale, 4 elems/thread ----
__global__ __launch_bounds__(256) void cvt16_kernel(const float* __restrict__ src,
                                                    ushort* __restrict__ dst,
                                                    float scale) {
    int i = blockIdx.x * 256 + threadIdx.x;
    float4 v = reinterpret_cast<const float4*>(src)[i];
    ushort4 o;
    o.x = f32_to_f16(v.x * scale); o.y = f32_to_f16(v.y * scale);
    o.z = f32_to_f16(v.z * scale); o.w = f32_to_f16(v.w * scale);
    reinterpret_cast<ushort4*>(dst)[i] = o;
}

// ---- e2[c] = sum(cb[c,:]^2) fp32 exact; one wave per row ----
__global__ __launch_bounds__(256) void e2_kernel(const float* __restrict__ cb,
                                                 float* __restrict__ e2) {
    int c = blockIdx.x * 4 + (threadIdx.x >> 6);
    int lane = threadIdx.x & 63;
    float4 v = reinterpret_cast<const float4*>(cb + (size_t)c * D)[lane];
    float s = v.x * v.x + v.y * v.y + v.z * v.z + v.w * v.w;
#pragma unroll
    for (int off = 32; off > 0; off >>= 1) s += __shfl_down(s, off);
    if (lane == 0) e2[c] = s;
}

__global__ __launch_bounds__(256) void xsq_kernel(const float* __restrict__ x,
                                                  float* __restrict__ xsq) {
    int t = blockIdx.x * 4 + (threadIdx.x >> 6);
    int lane = threadIdx.x & 63;
    float4 v = reinterpret_cast<const float4*>(x + (size_t)t * D)[lane];
    float s = v.x * v.x + v.y * v.y + v.z * v.z + v.w * v.w;
#pragma unroll
    for (int off = 32; off > 0; off >>= 1) s += __shfl_down(s, off);
    if (lane == 0) xsq[t] = s;
}

// ---- Pass 1: fp16 MFMA screening GEMM, m97 structure ----
// BK=32 K-loop, global_load_lds width-16 staging into linear [128][32] fp16
// tiles, 16 KB static LDS, 3 blocks/CU. MFMA call sequence (8 chained
// 16x16x32 over ascending k, identical fragments) is bit-identical to the
// previous one-shot-staging version, so bmin bits are unchanged.
__global__ __launch_bounds__(256, 3) void pass1_kernel(
    const ushort* __restrict__ xb, const ushort* __restrict__ cbb,
    const float* __restrict__ e2, ushort* __restrict__ bmin) {
    __shared__ ushort ash[128 * 32];
    __shared__ ushort bsh[128 * 32];
    const int tid = threadIdx.x;
    const int w = tid >> 6, l = tid & 63;
    const int wr = w >> 1, wc = w & 1;
    const int t0 = blockIdx.x * 128, n0 = blockIdx.y * 128;

    f32x4 acc[4][4];
#pragma unroll
    for (int mt = 0; mt < 4; ++mt)
#pragma unroll
        for (int nt = 0; nt < 4; ++nt) acc[mt][nt] = (f32x4)0.f;

    // Wave w stages LDS bytes [w*2048, (w+1)*2048) of each 8 KB tile via two
    // 1 KB wave-loads; HW writes lds_base + lane*16 (linear [128][32] fp16).
    const int byte0 = w * 2048 + l * 16;
    const int row0 = byte0 >> 6, c80 = (byte0 >> 4) & 3;
    const int byte1 = byte0 + 1024;
    const int row1 = byte1 >> 6, c81 = (byte1 >> 4) & 3;
    const ushort* ga0 = xb + (size_t)(t0 + row0) * D + c80 * 8;
    const ushort* ga1 = xb + (size_t)(t0 + row1) * D + c81 * 8;
    const ushort* gb0 = cbb + (size_t)(n0 + row0) * D + c80 * 8;
    const ushort* gb1 = cbb + (size_t)(n0 + row1) * D + c81 * 8;
    ushort* la0 = ash + w * 1024;        // shorts; wave-uniform
    ushort* la1 = ash + w * 1024 + 512;
    ushort* lb0 = bsh + w * 1024;
    ushort* lb1 = bsh + w * 1024 + 512;

    const ushort* xbase = ash + (wr * 64 + (l & 15)) * 32 + (l >> 4) * 8;
    const ushort* cbase = bsh + (wc * 64 + (l & 15)) * 32 + (l >> 4) * 8;

#pragma unroll
    for (int kt = 0; kt < 8; ++kt) {
        if (kt) __syncthreads();        // prev reads done before overwrite
        __builtin_amdgcn_global_load_lds((gbl_vp)(ga0 + kt * 32), (lds_vp)la0, 16, 0, 0);
        __builtin_amdgcn_global_load_lds((gbl_vp)(ga1 + kt * 32), (lds_vp)la1, 16, 0, 0);
        __builtin_amdgcn_global_load_lds((gbl_vp)(gb0 + kt * 32), (lds_vp)lb0, 16, 0, 0);
        __builtin_amdgcn_global_load_lds((gbl_vp)(gb1 + kt * 32), (lds_vp)lb1, 16, 0, 0);
        __syncthreads();                // drains vmcnt(0): staging visible
        f16x8 a[4], b[4];
#pragma unroll
        for (int mt = 0; mt < 4; ++mt)
            a[mt] = *reinterpret_cast<const f16x8*>(xbase + mt * 16 * 32);
#pragma unroll
        for (int nt = 0; nt < 4; ++nt)
            b[nt] = *reinterpret_cast<const f16x8*>(cbase + nt * 16 * 32);
#pragma unroll
        for (int mt = 0; mt < 4; ++mt)
#pragma unroll
            for (int nt = 0; nt < 4; ++nt)
                acc[mt][nt] = __builtin_amdgcn_mfma_f32_16x16x32_f16(
                    a[mt], b[nt], acc[mt][nt], 0, 0, 0);
    }

    float e2v[4];
#pragma unroll
    for (int nt = 0; nt < 4; ++nt)
        e2v[nt] = e2[n0 + wc * 64 + nt * 16 + (l & 15)];
    const int nb64 = blockIdx.y * 2 + wc;
#pragma unroll
    for (int mt = 0; mt < 4; ++mt) {
#pragma unroll
        for (int r = 0; r < 4; ++r) {
            float dm = fmaf(-UNSCALE2, acc[mt][0][r], e2v[0]);
#pragma unroll
            for (int nt = 1; nt < 4; ++nt)
                dm = fminf(dm, fmaf(-UNSCALE2, acc[mt][nt][r], e2v[nt]));
#pragma unroll
            for (int off = 1; off < 16; off <<= 1)
                dm = fminf(dm, __shfl_xor(dm, off));
            if ((l & 15) == 0) {
                int token = t0 + wr * 64 + mt * 16 + (l >> 4) * 4 + r;
                bmin[(size_t)token * NBLK + nb64] = f32_to_bf16(dm);
            }
        }
    }
}

// ---- Pass 2a: per-token min over 128 bf16 block-mins; init bestKey; and
// fold the TH flag-test here, appending (token) to per-nb candidate lists.
// Same values, same v <= min+TH comparison as the old in-pass2b test ->
// identical candidate set; list order is nondeterministic but the packed-key
// atomicMin winner is order-independent.
__global__ __launch_bounds__(256) void pass2a_kernel(
    const ushort* __restrict__ bmin, unsigned long long* __restrict__ bestKey,
    unsigned* __restrict__ cand, unsigned* __restrict__ counts) {
    int t = blockIdx.x * 256 + threadIdx.x;
    const uint4* bm = reinterpret_cast<const uint4*>(bmin + (size_t)t * NBLK);
    uint4 vv[16];
#pragma unroll
    for (int i = 0; i < 16; ++i) vv[i] = bm[i];
    float m = 3.4e38f;
#pragma unroll
    for (int i = 0; i < 16; ++i) {
        unsigned a[4] = {vv[i].x, vv[i].y, vv[i].z, vv[i].w};
#pragma unroll
        for (int j = 0; j < 4; ++j) {
            m = fminf(m, __uint_as_float(a[j] << 16));
            m = fminf(m, __uint_as_float(a[j] & 0xFFFF0000u));
        }
    }
    bestKey[t] = 0xFFFFFFFFFFFFFFFFULL;
    const float thr = m + TH;
#pragma unroll
    for (int i = 0; i < 16; ++i) {
        unsigned a[4] = {vv[i].x, vv[i].y, vv[i].z, vv[i].w};
#pragma unroll
        for (int j = 0; j < 4; ++j) {
            float lo = __uint_as_float(a[j] << 16);            // nb = 8i+2j
            float hi = __uint_as_float(a[j] & 0xFFFF0000u);    // nb = 8i+2j+1
            int nb = i * 8 + j * 2;
            if (lo <= thr) {
                unsigned s = atomicAdd(&counts[nb], 1u);
                if (s < CCAP) cand[(size_t)nb * CCAP + s] = (unsigned)t;
            }
            if (hi <= thr) {
                unsigned s = atomicAdd(&counts[nb + 1], 1u);
                if (s < CCAP) cand[(size_t)(nb + 1) * CCAP + s] = (unsigned)t;
            }
        }
    }
}

// ---- Pass 2b: exact fp32-chain rescan of compacted candidates ----
// NUMERICS: identical to the R2-verified bit-exact path — single sequential
// fma chain k=0..255 per (token, code), d = fl(fl(xsq+e2) - 2*dot), operand
// broadcast via v_readlane, shfl-xor tie-break (smallest index), packed-key
// atomicMin. Only the control flow changed: candidates now come from the
// per-nb compacted list, empty chunks exit before LDS staging, and 4 chains
// run in flight to amortize the csh reads (per-candidate op sequence kept).
__global__ __launch_bounds__(256, 2) void pass2b_kernel(
    const float* __restrict__ x, const float* __restrict__ cb,
    const float* __restrict__ e2, const float* __restrict__ xsq,
    const unsigned* __restrict__ cand, const unsigned* __restrict__ counts,
    unsigned long long* __restrict__ bestKey) {
    extern __shared__ float csh[];          // [256][65] cb^T fp32
    const int tid = threadIdx.x;
    const int nb = blockIdx.x;              // 64-code block
    int cnt = (int)counts[nb];
    if (cnt > CCAP) cnt = CCAP;
    const int base = blockIdx.y * PB;
    if (base >= cnt) return;                // uniform early-exit, pre-staging

    // stage 64 cb rows transposed (coalesced reads; 8-way writes, one-time)
#pragma unroll
    for (int r = 0; r < 16; ++r) {
        int i = r * 256 + tid;
        int row = i >> 6, kq = i & 63;
        float4 v = reinterpret_cast<const float4*>(cb + (size_t)(nb * CBS + row) * D)[kq];
        csh[(kq * 4 + 0) * 65 + row] = v.x;
        csh[(kq * 4 + 1) * 65 + row] = v.y;
        csh[(kq * 4 + 2) * 65 + row] = v.z;
        csh[(kq * 4 + 3) * 65 + row] = v.w;
    }
    __syncthreads();

    const int w = tid >> 6, j = tid & 63;
    const float e2v = e2[nb * CBS + j];
    const int ci0 = nb * CBS + j;
    const float4* X4 = reinterpret_cast<const float4*>(x);
    const unsigned* clist = cand + (size_t)nb * CCAP;

    int lo = base + w * 32;                 // this wave's slice of the chunk
    int hi = lo + 32; if (hi > cnt) hi = cnt;
    for (int p = lo; p < hi; p += 4) {
        int i1 = p + 1 < cnt ? p + 1 : cnt - 1;  // tail: replicate (idempotent)
        int i2 = p + 2 < cnt ? p + 2 : cnt - 1;
        int i3 = p + 3 < cnt ? p + 3 : cnt - 1;
        int t0 = (int)clist[p],  t1 = (int)clist[i1];
        int t2 = (int)clist[i2], t3 = (int)clist[i3];
        // lane j holds x[t][4j..4j+3]; coalesced, one load per candidate
        float4 v0 = X4[(size_t)t0 * 64 + j];
        float4 v1 = X4[(size_t)t1 * 64 + j];
        float4 v2 = X4[(size_t)t2 * 64 + j];
        float4 v3 = X4[(size_t)t3 * 64 + j];
        float a0 = 0.f, a1 = 0.f, a2 = 0.f, a3 = 0.f;
        // k ascending, ONE fma chain per (token, code) — bit-compat order.
#pragma unroll
        for (int kq = 0; kq < 64; ++kq) {
            float c0 = csh[(kq * 4 + 0) * 65 + j];
            float c1 = csh[(kq * 4 + 1) * 65 + j];
            float c2 = csh[(kq * 4 + 2) * 65 + j];
            float c3 = csh[(kq * 4 + 3) * 65 + j];
            a0 = fmaf(rdlane(v0.x, kq), c0, a0);
            a0 = fmaf(rdlane(v0.y, kq), c1, a0);
            a0 = fmaf(rdlane(v0.z, kq), c2, a0);
            a0 = fmaf(rdlane(v0.w, kq), c3, a0);
            a1 = fmaf(rdlane(v1.x, kq), c0, a1);
            a1 = fmaf(rdlane(v1.y, kq), c1, a1);
            a1 = fmaf(rdlane(v1.z, kq), c2, a1);
            a1 = fmaf(rdlane(v1.w, kq), c3, a1);
            a2 = fmaf(rdlane(v2.x, kq), c0, a2);
            a2 = fmaf(rdlane(v2.y, kq), c1, a2);
            a2 = fmaf(rdlane(v2.z, kq), c2, a2);
            a2 = fmaf(rdlane(v2.w, kq), c3, a2);
            a3 = fmaf(rdlane(v3.x, kq), c0, a3);
            a3 = fmaf(rdlane(v3.y, kq), c1, a3);
            a3 = fmaf(rdlane(v3.z, kq), c2, a3);
            a3 = fmaf(rdlane(v3.w, kq), c3, a3);
        }
        float av[4] = {a0, a1, a2, a3};
        int tv[4] = {t0, t1, t2, t3};
#pragma unroll
        for (int g = 0; g < 4; ++g) {
            float dd = fmaf(-2.f, av[g], xsq[tv[g]] + e2v);
            int ci = ci0;
#pragma unroll
            for (int off = 1; off < 64; off <<= 1) {
                float od = __shfl_xor(dd, off);
                int oc = __shfl_xor(ci, off);
                if (od < dd || (od == dd && oc < ci)) { dd = od; ci = oc; }
            }
            if (j == 0) {
                unsigned u = __float_as_uint(dd);
                u = (u & 0x80000000u) ? ~u : (u | 0x80000000u);
                unsigned long long key =
                    ((unsigned long long)u << 32) | (unsigned)ci;
                atomicMin(bestKey + tv[g], key);
            }
        }
    }
}

// ---- Pass 3: gather codebook row, emit quantized + idx + partial loss ----
__global__ __launch_bounds__(256) void gather_kernel(
    const float* __restrict__ x, const float* __restrict__ cb,
    const unsigned long long* __restrict__ bestKey,
    float* __restrict__ out, float* __restrict__ partial) {
    __shared__ float red[4];
    const int token = blockIdx.x;
    const int tid = threadIdx.x;
    int idx = (int)(bestKey[token] & 0xFFFFFFFFULL);
    if ((unsigned)idx >= (unsigned)KCODES) idx = 0;  // defensive: no OOB access
    float q = cb[(size_t)idx * D + tid];
    float xv = x[(size_t)token * D + tid];
    out[(size_t)token * D + tid] = q;
    float d = q - xv;
    d = d * d;
#pragma unroll
    for (int off = 32; off > 0; off >>= 1) d += __shfl_down(d, off);
    if ((tid & 63) == 0) red[tid >> 6] = d;
    __syncthreads();
    if (tid == 0) {
        partial[token] = red[0] + red[1] + red[2] + red[3];
        out[(size_t)QSIZE + token] = (float)idx;
    }
}

__global__ __launch_bounds__(256) void loss_kernel(const float* __restrict__ partial,
                                                   float* __restrict__ out) {
    __shared__ float red[4];
    float s = 0.f;
    for (int i = threadIdx.x; i < NTOK; i += 256) s += partial[i];
#pragma unroll
    for (int off = 32; off > 0; off >>= 1) s += __shfl_down(s, off);
    if ((threadIdx.x & 63) == 0) red[threadIdx.x >> 6] = s;
    __syncthreads();
    if (threadIdx.x == 0) {
        float total = red[0] + red[1] + red[2] + red[3];
        out[(size_t)QSIZE + NTOK] = 0.25f * total / (float)QSIZE;
    }
}

extern "C" void kernel_launch(void* const* d_in, const int* in_sizes, int n_in,
                              void* d_out, int out_size, void* d_ws, size_t ws_size,
                              hipStream_t stream) {
    const float* x = (const float*)d_in[0];     // [16384, 256]
    const float* cb = (const float*)d_in[1];    // [8192, 256]
    float* out = (float*)d_out;
    float* ws = (float*)d_ws;

    // d_out doubles as scratch (fully overwritten by pass 3 + index writes):
    //   [0, 8M): xb fp16 (pass1 input) -> reused as cand u32 [128][4096] (2 MB)
    //   [8M, 12M): bmin bf16 [NTOK][128] | [12M, 16M): cbb fp16
    //   [16M, 16M+512): counts u32[128] (inside the idx-output region;
    //                   written pre-pass2a, dead after pass2b, overwritten by gather)
    ushort* xb = (ushort*)d_out;
    ushort* bmin = (ushort*)((char*)d_out + 8388608);
    ushort* cbb = (ushort*)((char*)d_out + 12582912);
    unsigned* cand = (unsigned*)d_out;
    unsigned* counts = (unsigned*)((char*)d_out + 16777216);

    // ws (floats): e2[8192] | xsq[16384] | (unused rowmin slot) | partial[16384]
    //              | bestKey u64[16384]   (layout unchanged from prior rounds)
    float* e2 = ws;
    float* xsq = ws + 8192;
    float* partial = ws + 8192 + 2 * 16384;
    unsigned long long* bestKey = (unsigned long long*)(ws + 8192 + 3 * 16384);

    hipFuncSetAttribute((const void*)pass2b_kernel,
                        hipFuncAttributeMaxDynamicSharedMemorySize, P2_LDS);

    cvt16_kernel<<<QSIZE / 1024, 256, 0, stream>>>(x, xb, 1.0f);
    cvt16_kernel<<<KCODES * D / 1024, 256, 0, stream>>>(cb, cbb, CBSCALE);
    e2_kernel<<<KCODES / 4, 256, 0, stream>>>(cb, e2);
    xsq_kernel<<<NTOK / 4, 256, 0, stream>>>(x, xsq);
    pass1_kernel<<<dim3(NTOK / 128, KCODES / 128), 256, 0, stream>>>(xb, cbb, e2, bmin);
    hipMemsetAsync(counts, 0, NBLK * sizeof(unsigned), stream);
    pass2a_kernel<<<NTOK / 256, 256, 0, stream>>>(bmin, bestKey, cand, counts);
    pass2b_kernel<<<dim3(NBLK, CCAP / PB), 256, P2_LDS, stream>>>(
        x, cb, e2, xsq, cand, counts, bestKey);
    gather_kernel<<<NTOK, 256, 0, stream>>>(x, cb, bestKey, out, partial);
    loss_kernel<<<1, 256, 0, stream>>>(partial, out);
}